// Round 19
// baseline (75.856 us; speedup 1.0000x reference)
//
#include <hip/hip_runtime.h>
#include <hip/hip_bf16.h>

// EventSpecificTimingHeads: E=16 per-event attention heads on shared features.
// Round 19: attn = r15 barrier-free form + s_setprio(1) around MFMA/exp
// cluster (T5; m191: helps when waves drift, which barrier-free enables) +
// explicit next-kt ka/va register prefetch (hides ~120cyc ds_read latency
// under prev step's compute). qkv r17 / head r16 / convert unchanged.

#define E_ 16
#define B_ 8
#define S_ 512
#define D_ 128
#define H_ 4
#define DH_ 32
#define H2_ 64
#define M_ (B_ * S_)
// 1/sqrt(32) * log2(e): scores come out of QK^T in log2 domain.
#define QK_SCALE_L2E 0.25503472437616588f

#define ATTN_LDS_BYTES (512 * 80 + 32 * 1040)       // 74240
#define HEAD_LDS_BYTES (128 * 136 * 2 * 2)          // 69632
#define QKV_LDS_BYTES  (128 * 136 * 2 * 2)          // 69632

typedef __attribute__((ext_vector_type(4))) short bf16x4;
typedef __attribute__((ext_vector_type(8))) short bf16x8;
typedef __attribute__((ext_vector_type(4))) float f32x4;

__device__ __forceinline__ short f2bf(float f) {
    unsigned u = __builtin_bit_cast(unsigned, f);
    u += 0x7fffu + ((u >> 16) & 1u);   // RNE
    return (short)(u >> 16);
}

__device__ __forceinline__ unsigned pk2(float lo, float hi) {
    __hip_bfloat162 t = __float22bfloat162_rn(make_float2(lo, hi));
    unsigned r;
    __builtin_memcpy(&r, &t, sizeof(r));
    return r;
}

__device__ __forceinline__ bf16x8 cat8(bf16x4 lo, bf16x4 hi) {
    return __builtin_shufflevector(lo, hi, 0, 1, 2, 3, 4, 5, 6, 7);
}

// ---------------------------------------------------------------------------
// Kernel 0: fp32 -> bf16 convert: x, Wqkv, Wo, W1. (convert once, read many)
// ---------------------------------------------------------------------------
__global__ __launch_bounds__(256) void convert_kernel(
    const float* __restrict__ x, const float* __restrict__ w,
    const float* __restrict__ wo, const float* __restrict__ w1,
    short* __restrict__ xbf, short* __restrict__ wbf,
    short* __restrict__ wobf, short* __restrict__ w1bf)
{
    const int XN  = (M_ * D_) / 8;             // 65536
    const int WN  = (E_ * 3 * D_ * D_) / 8;    // 98304
    const int WON = (E_ * D_ * D_) / 8;        // 32768
    const int W1N = (E_ * H2_ * D_) / 8;       // 16384
    int idx = blockIdx.x * 256 + threadIdx.x;
    const float* src; short* dst; int off;
    if (idx < XN)                        { src = x;  dst = xbf;  off = idx; }
    else if (idx < XN + WN)              { src = w;  dst = wbf;  off = idx - XN; }
    else if (idx < XN + WN + WON)        { src = wo; dst = wobf; off = idx - XN - WN; }
    else if (idx < XN + WN + WON + W1N)  { src = w1; dst = w1bf; off = idx - XN - WN - WON; }
    else return;
    float4 v0 = *(const float4*)&src[(size_t)off * 8];
    float4 v1 = *(const float4*)&src[(size_t)off * 8 + 4];
    bf16x8 o;
    o[0] = f2bf(v0.x); o[1] = f2bf(v0.y); o[2] = f2bf(v0.z); o[3] = f2bf(v0.w);
    o[4] = f2bf(v1.x); o[5] = f2bf(v1.y); o[6] = f2bf(v1.z); o[7] = f2bf(v1.w);
    *(bf16x8*)&dst[(size_t)off * 8] = o;
}

// ---------------------------------------------------------------------------
// Kernel 1: QKV GEMM, 512-thr blocks, 128x128 tiles (unchanged from r17).
// ---------------------------------------------------------------------------
__global__ __launch_bounds__(512) void qkv_mfma_kernel(
    const short* __restrict__ xbf,   // [4096][128] bf16
    const short* __restrict__ wbf,   // [16][384][128] bf16
    const float* __restrict__ bqkv,  // [16][384]
    short* __restrict__ q, short* __restrict__ k, short* __restrict__ v)
{
    extern __shared__ __align__(16) char lds[];
    short (*xs)[136] = (short(*)[136])lds;
    short (*ws)[136] = (short(*)[136])(lds + 128 * 136 * 2);

    const int ct2 = blockIdx.x;  // 0..2
    const int rt  = blockIdx.y;  // 0..31
    const int e   = blockIdx.z;  // 0..15
    const int tid = threadIdx.x;
    const int w    = tid >> 6;
    const int lane = tid & 63;
    const int l15  = lane & 15;
    const int g    = lane >> 4;

    #pragma unroll
    for (int p = 0; p < 4; ++p) {
        int idx = tid + p * 512;
        int row = idx >> 4, c8 = (idx & 15) * 8;
        *(bf16x8*)&xs[row][c8] =
            *(const bf16x8*)&xbf[(size_t)(rt * 128 + row) * 128 + c8];
        *(bf16x8*)&ws[row][c8] =
            *(const bf16x8*)&wbf[((size_t)e * 384 + ct2 * 128 + row) * 128 + c8];
    }
    __syncthreads();

    const int m0 = (w >> 2) * 64;
    const int n0 = (w & 3) * 32;
    f32x4 acc[4][2] = {};

    #pragma unroll
    for (int kk = 0; kk < 128; kk += 32) {
        bf16x8 A0 = cat8(*(const bf16x4*)&ws[n0      + l15][kk + 4 * g],
                         *(const bf16x4*)&ws[n0      + l15][kk + 16 + 4 * g]);
        bf16x8 A1 = cat8(*(const bf16x4*)&ws[n0 + 16 + l15][kk + 4 * g],
                         *(const bf16x4*)&ws[n0 + 16 + l15][kk + 16 + 4 * g]);
        #pragma unroll
        for (int mm = 0; mm < 4; ++mm) {
            bf16x8 Bm = cat8(*(const bf16x4*)&xs[m0 + mm * 16 + l15][kk + 4 * g],
                             *(const bf16x4*)&xs[m0 + mm * 16 + l15][kk + 16 + 4 * g]);
            acc[mm][0] = __builtin_amdgcn_mfma_f32_16x16x32_bf16(A0, Bm, acc[mm][0], 0, 0, 0);
            acc[mm][1] = __builtin_amdgcn_mfma_f32_16x16x32_bf16(A1, Bm, acc[mm][1], 0, 0, 0);
        }
    }

    if (ct2 < 2) {
        short* dst = (ct2 == 0) ? q : k;
        const float scale = (ct2 == 0) ? QK_SCALE_L2E : 1.0f;
        #pragma unroll
        for (int mm = 0; mm < 4; ++mm) {
            #pragma unroll
            for (int nn = 0; nn < 2; ++nn) {
                const int d  = n0 + nn * 16 + 4 * g;
                const int h  = d >> 5, dh = d & 31;
                const int jb = ct2 * 128 + d;
                const float b0 = bqkv[e * 384 + jb + 0];
                const float b1 = bqkv[e * 384 + jb + 1];
                const float b2 = bqkv[e * 384 + jb + 2];
                const float b3 = bqkv[e * 384 + jb + 3];
                const int m  = rt * 128 + m0 + mm * 16 + l15;
                const int bb = m >> 9, s = m & 511;
                bf16x4 o;
                o[0] = f2bf((acc[mm][nn][0] + b0) * scale);
                o[1] = f2bf((acc[mm][nn][1] + b1) * scale);
                o[2] = f2bf((acc[mm][nn][2] + b2) * scale);
                o[3] = f2bf((acc[mm][nn][3] + b3) * scale);
                *(bf16x4*)&dst[((((size_t)e * B_ + bb) * H_ + h) * S_ + s) * DH_ + dh] = o;
            }
        }
    } else {
        __syncthreads();
        float (*rp)[132] = (float(*)[132])lds;
        #pragma unroll
        for (int mm = 0; mm < 4; ++mm) {
            #pragma unroll
            for (int nn = 0; nn < 2; ++nn) {
                const int jl = n0 + nn * 16 + 4 * g;
                const int ml = m0 + mm * 16 + l15;
                rp[jl + 0][ml] = acc[mm][nn][0];
                rp[jl + 1][ml] = acc[mm][nn][1];
                rp[jl + 2][ml] = acc[mm][nn][2];
                rp[jl + 3][ml] = acc[mm][nn][3];
            }
        }
        __syncthreads();
        const int bb = (rt * 128) >> 9;
        const int sb = (rt * 128) & 511;
        #pragma unroll
        for (int p = 0; p < 4; ++p) {
            int task = tid + p * 512;
            int jl = task >> 4, sc = (task & 15) * 8;
            const int h = jl >> 5, dh = jl & 31;
            const float bias = bqkv[e * 384 + 256 + jl];
            bf16x8 o;
            #pragma unroll
            for (int j = 0; j < 8; ++j) o[j] = f2bf(rp[jl][sc + j] + bias);
            *(bf16x8*)&v[((((size_t)e * B_ + bb) * H_ + h) * DH_ + dh) * S_ + sb + sc] = o;
        }
    }
}

// ---------------------------------------------------------------------------
// Kernel 2: flash attention, barrier-free + frag prefetch + setprio.
// One block per (e,bh): 8 waves x 64 q-rows (4 qf/wave). Full K + V^T in
// dynamic LDS (74.2 KB), staged once; zero inner barriers.
// ---------------------------------------------------------------------------
__global__ __launch_bounds__(512) void attn_kernel(
    const short* __restrict__ q, const short* __restrict__ k,
    const short* __restrict__ vt, short* __restrict__ ctxbf)
{
    extern __shared__ __align__(16) char smem[];
    char* Kbase  = smem;            // [512 rows][80 B]
    char* VTbase = smem + 40960;    // [32 rows][1040 B]

    const int bh  = blockIdx.x;   // 0..31
    const int e   = blockIdx.y;   // 0..15
    const int tid = threadIdx.x;
    const int w    = tid >> 6;
    const int lane = tid & 63;
    const int l15  = lane & 15;
    const int g    = lane >> 4;

    const size_t base = ((size_t)e * 32 + bh) * (S_ * DH_);
    const short* qg = q  + base;
    const short* kg = k  + base;
    const short* vg = vt + base;

    // ---- stage full K: thread t copies row t (64 B) ----
    {
        const uint4* src = (const uint4*)(kg + (size_t)tid * DH_);
        uint4* dst = (uint4*)(Kbase + (size_t)tid * 80);
        dst[0] = src[0]; dst[1] = src[1]; dst[2] = src[2]; dst[3] = src[3];
    }
    // ---- stage full V^T ----
    {
        int d = tid >> 4, c0 = (tid & 15) * 32;
        const uint4* src = (const uint4*)(vg + (size_t)d * S_ + c0);
        uint4* dst = (uint4*)(VTbase + (size_t)d * 1040 + c0 * 2);
        dst[0] = src[0]; dst[1] = src[1]; dst[2] = src[2]; dst[3] = src[3];
    }
    // ---- Q fragments: 4 per wave ----
    bf16x8 bq[4];
    #pragma unroll
    for (int qf = 0; qf < 4; ++qf) {
        const short* qp = qg + (size_t)(w * 64 + qf * 16 + l15) * DH_;
        bq[qf] = cat8(*(const bf16x4*)(qp + 4 * g),
                      *(const bf16x4*)(qp + 16 + 4 * g));
    }
    __syncthreads();   // the ONLY barrier

    f32x4 acc0[4] = {}, acc1[4] = {};
    float lsum[4] = {0.f, 0.f, 0.f, 0.f};

    // frag load helper offsets
    const char* kO = Kbase + (size_t)l15 * 80 + g * 8;          // + row_l*80 more
    const char* vO = VTbase + (size_t)l15 * 1040 + (4 * g) * 2; // + keyb*2 more

    // prefetch kt = 0
    bf16x8 ka0c, ka1c, va0c, va1c;
    {
        const char* kp = kO;                       // rows 0*16.. and 1*16..
        ka0c = cat8(*(const bf16x4*)kp, *(const bf16x4*)(kp + 32));
        ka1c = cat8(*(const bf16x4*)(kp + 16 * 80), *(const bf16x4*)(kp + 16 * 80 + 32));
        const char* vp = vO;
        va0c = cat8(*(const bf16x4*)vp, *(const bf16x4*)(vp + 32));
        const char* vq = vp + 16 * 1040;
        va1c = cat8(*(const bf16x4*)vq, *(const bf16x4*)(vq + 32));
    }

    #pragma unroll 1
    for (int kt = 0; kt < 16; ++kt) {
        // ---- issue next-kt frag loads early (wraps harmlessly at kt=15) ----
        const int ktn = (kt + 1) & 15;
        bf16x8 ka0n, ka1n, va0n, va1n;
        {
            const char* kp = kO + (size_t)(ktn * 32) * 80;
            ka0n = cat8(*(const bf16x4*)kp, *(const bf16x4*)(kp + 32));
            ka1n = cat8(*(const bf16x4*)(kp + 16 * 80), *(const bf16x4*)(kp + 16 * 80 + 32));
            const char* vp = vO + (size_t)(ktn * 32) * 2;
            va0n = cat8(*(const bf16x4*)vp, *(const bf16x4*)(vp + 32));
            const char* vq = vp + 16 * 1040;
            va1n = cat8(*(const bf16x4*)vq, *(const bf16x4*)(vq + 32));
        }

        __builtin_amdgcn_s_setprio(1);
        #pragma unroll
        for (int qf = 0; qf < 4; ++qf) {
            f32x4 z = {0.f, 0.f, 0.f, 0.f};
            f32x4 s0 = __builtin_amdgcn_mfma_f32_16x16x32_bf16(ka0c, bq[qf], z, 0, 0, 0);
            f32x4 s1 = __builtin_amdgcn_mfma_f32_16x16x32_bf16(ka1c, bq[qf], z, 0, 0, 0);
            float p0 = __builtin_amdgcn_exp2f(s0[0]);
            float p1 = __builtin_amdgcn_exp2f(s0[1]);
            float p2 = __builtin_amdgcn_exp2f(s0[2]);
            float p3 = __builtin_amdgcn_exp2f(s0[3]);
            float p4 = __builtin_amdgcn_exp2f(s1[0]);
            float p5 = __builtin_amdgcn_exp2f(s1[1]);
            float p6 = __builtin_amdgcn_exp2f(s1[2]);
            float p7 = __builtin_amdgcn_exp2f(s1[3]);
            lsum[qf] += ((p0 + p1) + (p2 + p3)) + ((p4 + p5) + (p6 + p7));
            uint4 uu = make_uint4(pk2(p0, p1), pk2(p2, p3),
                                  pk2(p4, p5), pk2(p6, p7));
            bf16x8 pf = __builtin_bit_cast(bf16x8, uu);
            acc0[qf] = __builtin_amdgcn_mfma_f32_16x16x32_bf16(va0c, pf, acc0[qf], 0, 0, 0);
            acc1[qf] = __builtin_amdgcn_mfma_f32_16x16x32_bf16(va1c, pf, acc1[qf], 0, 0, 0);
        }
        __builtin_amdgcn_s_setprio(0);

        ka0c = ka0n; ka1c = ka1n; va0c = va0n; va1c = va1n;
    }

    // ---- denominators + ctx write (bf16 row-major [e][b][s][128]) ----
    const int b = bh >> 2, h = bh & 3;
    #pragma unroll
    for (int qf = 0; qf < 4; ++qf) {
        float ls = lsum[qf];
        ls += __shfl_xor(ls, 16);
        ls += __shfl_xor(ls, 32);
        const float inv = 1.0f / ls;
        const int qrow = w * 64 + qf * 16 + l15;
        short* cg = ctxbf + (((size_t)(e * B_ + b) * S_ + qrow) * D_ + h * DH_);
        bf16x4 o0, o1;
        #pragma unroll
        for (int r = 0; r < 4; ++r) {
            o0[r] = f2bf(acc0[qf][r] * inv);
            o1[r] = f2bf(acc1[qf][r] * inv);
        }
        *(bf16x4*)&cg[4 * g]      = o0;
        *(bf16x4*)&cg[16 + 4 * g] = o1;
    }
}

// ---------------------------------------------------------------------------
// Kernel 3: head, 512-thr blocks, 128 rows (unchanged from r16/r17).
// ---------------------------------------------------------------------------
__global__ __launch_bounds__(512) void head_mfma_kernel(
    const short* __restrict__ ctxbf,  // [E][4096][128] bf16
    const short* __restrict__ wobf,   // [E][128][128] bf16
    const float* __restrict__ bo,     // [E][128]
    const short* __restrict__ w1bf,   // [E][64][128] bf16
    const float* __restrict__ b1,     // [E][64]
    const float* __restrict__ W2,     // [E][64]
    const float* __restrict__ b2,     // [E]
    float* __restrict__ out)          // [B][S][E]
{
    extern __shared__ __align__(16) char smem[];
    short (*Wos)[136] = (short(*)[136])smem;
    short (*cts)[136] = (short(*)[136])(smem + 128 * 136 * 2);

    const int mt  = blockIdx.x;   // 0..31
    const int e   = blockIdx.y;
    const int tid = threadIdx.x;
    const int w    = tid >> 6;
    const int lane = tid & 63;
    const int l15  = lane & 15;
    const int g    = lane >> 4;

    #pragma unroll
    for (int p = 0; p < 4; ++p) {
        int idx = tid + p * 512;
        int row = idx >> 4, c8 = (idx & 15) * 8;
        *(bf16x8*)&Wos[row][c8] =
            *(const bf16x8*)&wobf[((size_t)e * 128 + row) * 128 + c8];
        *(bf16x8*)&cts[row][c8] =
            *(const bf16x8*)&ctxbf[((size_t)e * M_ + mt * 128 + row) * 128 + c8];
    }
    __syncthreads();

    f32x4 accA[8] = {};
    #pragma unroll
    for (int kk = 0; kk < 128; kk += 32) {
        bf16x8 a = cat8(*(const bf16x4*)&cts[w * 16 + l15][kk + 4 * g],
                        *(const bf16x4*)&cts[w * 16 + l15][kk + 16 + 4 * g]);
        #pragma unroll
        for (int t = 0; t < 8; ++t) {
            bf16x8 bfr = cat8(*(const bf16x4*)&Wos[t * 16 + l15][kk + 4 * g],
                              *(const bf16x4*)&Wos[t * 16 + l15][kk + 16 + 4 * g]);
            accA[t] = __builtin_amdgcn_mfma_f32_16x16x32_bf16(a, bfr, accA[t], 0, 0, 0);
        }
    }
    __syncthreads();

    #pragma unroll
    for (int p = 0; p < 2; ++p) {
        int idx = tid + p * 512;
        int row = idx >> 4, c8 = (idx & 15) * 8;
        *(bf16x8*)&Wos[row][c8] =
            *(const bf16x8*)&w1bf[((size_t)e * 64 + row) * 128 + c8];
    }
    #pragma unroll
    for (int t = 0; t < 8; ++t) {
        const float bov = bo[e * 128 + t * 16 + l15];
        #pragma unroll
        for (int r = 0; r < 4; ++r)
            cts[w * 16 + 4 * g + r][t * 16 + l15] = f2bf(accA[t][r] + bov);
    }
    __syncthreads();

    f32x4 accB[4] = {};
    #pragma unroll
    for (int kk = 0; kk < 128; kk += 32) {
        bf16x8 a = cat8(*(const bf16x4*)&cts[w * 16 + l15][kk + 4 * g],
                        *(const bf16x4*)&cts[w * 16 + l15][kk + 16 + 4 * g]);
        #pragma unroll
        for (int t = 0; t < 4; ++t) {
            bf16x8 bfr = cat8(*(const bf16x4*)&Wos[t * 16 + l15][kk + 4 * g],
                              *(const bf16x4*)&Wos[t * 16 + l15][kk + 16 + 4 * g]);
            accB[t] = __builtin_amdgcn_mfma_f32_16x16x32_bf16(a, bfr, accB[t], 0, 0, 0);
        }
    }

    float b1v[4], w2v[4];
    #pragma unroll
    for (int t = 0; t < 4; ++t) {
        b1v[t] = b1[e * 64 + t * 16 + l15];
        w2v[t] = W2[e * 64 + t * 16 + l15];
    }
    const float b2v = b2[e];
    #pragma unroll
    for (int r = 0; r < 4; ++r) {
        float s = 0.f;
        #pragma unroll
        for (int t = 0; t < 4; ++t)
            s += fmaxf(accB[t][r] + b1v[t], 0.f) * w2v[t];
        s += __shfl_xor(s, 1);
        s += __shfl_xor(s, 2);
        s += __shfl_xor(s, 4);
        s += __shfl_xor(s, 8);
        if (l15 == 0) {
            const int m = mt * 128 + w * 16 + 4 * g + r;
            const int bb = m >> 9, ss = m & 511;
            out[((size_t)(bb * S_ + ss)) * E_ + e] = s + b2v;
        }
    }
}

// ---------------------------------------------------------------------------
extern "C" void kernel_launch(void* const* d_in, const int* in_sizes, int n_in,
                              void* d_out, int out_size, void* d_ws, size_t ws_size,
                              hipStream_t stream) {
    const float* x    = (const float*)d_in[0];
    const float* Wqkv = (const float*)d_in[1];
    const float* bqkv = (const float*)d_in[2];
    const float* Wo   = (const float*)d_in[3];
    const float* bo   = (const float*)d_in[4];
    const float* W1   = (const float*)d_in[5];
    const float* b1   = (const float*)d_in[6];
    const float* W2   = (const float*)d_in[7];
    const float* b2   = (const float*)d_in[8];
    float* out = (float*)d_out;

    const size_t SZ = (size_t)E_ * B_ * H_ * S_ * DH_;  // 8,388,608 elements
    short* qb    = (short*)d_ws;
    short* kb    = qb + SZ;
    short* vtb   = kb + SZ;
    short* ctxbf = vtb + SZ;                 // [E][4096][128] bf16
    short* xbf   = ctxbf + SZ;               // 524288
    short* wbf   = xbf + (size_t)M_ * D_;    // 786432
    short* wobf  = wbf + (size_t)E_ * 3 * D_ * D_;   // 262144
    short* w1bf  = wobf + (size_t)E_ * D_ * D_;      // 131072

    hipFuncSetAttribute((const void*)qkv_mfma_kernel,
                        hipFuncAttributeMaxDynamicSharedMemorySize,
                        QKV_LDS_BYTES);
    hipFuncSetAttribute((const void*)attn_kernel,
                        hipFuncAttributeMaxDynamicSharedMemorySize,
                        ATTN_LDS_BYTES);
    hipFuncSetAttribute((const void*)head_mfma_kernel,
                        hipFuncAttributeMaxDynamicSharedMemorySize,
                        HEAD_LDS_BYTES);

    convert_kernel<<<dim3(832), 256, 0, stream>>>(x, Wqkv, Wo, W1, xbf, wbf, wobf, w1bf);
    qkv_mfma_kernel<<<dim3(3, 32, 16), 512, QKV_LDS_BYTES, stream>>>(xbf, wbf, bqkv, qb, kb, vtb);
    attn_kernel<<<dim3(32, 16), 512, ATTN_LDS_BYTES, stream>>>(qb, kb, vtb, ctxbf);
    head_mfma_kernel<<<dim3(32, 16), 512, HEAD_LDS_BYTES, stream>>>(ctxbf, wobf, bo, w1bf, b1, W2, b2, out);
}

// Round 20
// 69.562 us; speedup vs baseline: 1.0905x; 1.0905x over previous
//
#include <hip/hip_runtime.h>
#include <hip/hip_bf16.h>

// EventSpecificTimingHeads: E=16 per-event attention heads on shared features.
// Round 20: instruction-count attack. (1) softmax denominator via ones-MFMA
// (full k=32 contraction -> kills 8 VALU adds per qf-kt AND both epilogue
// shuffles); (2) contiguous-k fragment convention (k-slot(g,j)=8g+j) ->
// every cat8(2x b64) becomes one ds_read_b128 in qkv/head/QK^T (valid by
// common-k-permutation invariance, HW-validated since r7); (3) r19's
// setprio/prefetch reverted (measured negative). attn base = r15 barrier-free.

#define E_ 16
#define B_ 8
#define S_ 512
#define D_ 128
#define H_ 4
#define DH_ 32
#define H2_ 64
#define M_ (B_ * S_)
// 1/sqrt(32) * log2(e): scores come out of QK^T in log2 domain.
#define QK_SCALE_L2E 0.25503472437616588f

#define ATTN_LDS_BYTES (512 * 80 + 32 * 1040)       // 74240
#define HEAD_LDS_BYTES (128 * 136 * 2 * 2)          // 69632
#define QKV_LDS_BYTES  (128 * 136 * 2 * 2)          // 69632

typedef __attribute__((ext_vector_type(4))) short bf16x4;
typedef __attribute__((ext_vector_type(8))) short bf16x8;
typedef __attribute__((ext_vector_type(4))) float f32x4;

__device__ __forceinline__ short f2bf(float f) {
    unsigned u = __builtin_bit_cast(unsigned, f);
    u += 0x7fffu + ((u >> 16) & 1u);   // RNE
    return (short)(u >> 16);
}

__device__ __forceinline__ unsigned pk2(float lo, float hi) {
    __hip_bfloat162 t = __float22bfloat162_rn(make_float2(lo, hi));
    unsigned r;
    __builtin_memcpy(&r, &t, sizeof(r));
    return r;
}

__device__ __forceinline__ bf16x8 cat8(bf16x4 lo, bf16x4 hi) {
    return __builtin_shufflevector(lo, hi, 0, 1, 2, 3, 4, 5, 6, 7);
}

// ---------------------------------------------------------------------------
// Kernel 0: fp32 -> bf16 convert: x, Wqkv, Wo, W1. (convert once, read many)
// ---------------------------------------------------------------------------
__global__ __launch_bounds__(256) void convert_kernel(
    const float* __restrict__ x, const float* __restrict__ w,
    const float* __restrict__ wo, const float* __restrict__ w1,
    short* __restrict__ xbf, short* __restrict__ wbf,
    short* __restrict__ wobf, short* __restrict__ w1bf)
{
    const int XN  = (M_ * D_) / 8;             // 65536
    const int WN  = (E_ * 3 * D_ * D_) / 8;    // 98304
    const int WON = (E_ * D_ * D_) / 8;        // 32768
    const int W1N = (E_ * H2_ * D_) / 8;       // 16384
    int idx = blockIdx.x * 256 + threadIdx.x;
    const float* src; short* dst; int off;
    if (idx < XN)                        { src = x;  dst = xbf;  off = idx; }
    else if (idx < XN + WN)              { src = w;  dst = wbf;  off = idx - XN; }
    else if (idx < XN + WN + WON)        { src = wo; dst = wobf; off = idx - XN - WN; }
    else if (idx < XN + WN + WON + W1N)  { src = w1; dst = w1bf; off = idx - XN - WN - WON; }
    else return;
    float4 v0 = *(const float4*)&src[(size_t)off * 8];
    float4 v1 = *(const float4*)&src[(size_t)off * 8 + 4];
    bf16x8 o;
    o[0] = f2bf(v0.x); o[1] = f2bf(v0.y); o[2] = f2bf(v0.z); o[3] = f2bf(v0.w);
    o[4] = f2bf(v1.x); o[5] = f2bf(v1.y); o[6] = f2bf(v1.z); o[7] = f2bf(v1.w);
    *(bf16x8*)&dst[(size_t)off * 8] = o;
}

// ---------------------------------------------------------------------------
// Kernel 1: QKV GEMM, 512-thr blocks, 128x128 tiles. Contiguous-k frags
// (single b128 LDS reads, no cat8). Epilogues unchanged (D layout is fixed).
// ---------------------------------------------------------------------------
__global__ __launch_bounds__(512) void qkv_mfma_kernel(
    const short* __restrict__ xbf,   // [4096][128] bf16
    const short* __restrict__ wbf,   // [16][384][128] bf16
    const float* __restrict__ bqkv,  // [16][384]
    short* __restrict__ q, short* __restrict__ k, short* __restrict__ v)
{
    extern __shared__ __align__(16) char lds[];
    short (*xs)[136] = (short(*)[136])lds;
    short (*ws)[136] = (short(*)[136])(lds + 128 * 136 * 2);

    const int ct2 = blockIdx.x;  // 0..2
    const int rt  = blockIdx.y;  // 0..31
    const int e   = blockIdx.z;  // 0..15
    const int tid = threadIdx.x;
    const int w    = tid >> 6;
    const int lane = tid & 63;
    const int l15  = lane & 15;
    const int g    = lane >> 4;

    #pragma unroll
    for (int p = 0; p < 4; ++p) {
        int idx = tid + p * 512;
        int row = idx >> 4, c8 = (idx & 15) * 8;
        *(bf16x8*)&xs[row][c8] =
            *(const bf16x8*)&xbf[(size_t)(rt * 128 + row) * 128 + c8];
        *(bf16x8*)&ws[row][c8] =
            *(const bf16x8*)&wbf[((size_t)e * 384 + ct2 * 128 + row) * 128 + c8];
    }
    __syncthreads();

    const int m0 = (w >> 2) * 64;
    const int n0 = (w & 3) * 32;
    f32x4 acc[4][2] = {};

    #pragma unroll
    for (int kk = 0; kk < 128; kk += 32) {
        // contiguous-k: lane (row, g) holds k = kk + 8g .. kk + 8g+7
        bf16x8 A0 = *(const bf16x8*)&ws[n0      + l15][kk + 8 * g];
        bf16x8 A1 = *(const bf16x8*)&ws[n0 + 16 + l15][kk + 8 * g];
        #pragma unroll
        for (int mm = 0; mm < 4; ++mm) {
            bf16x8 Bm = *(const bf16x8*)&xs[m0 + mm * 16 + l15][kk + 8 * g];
            acc[mm][0] = __builtin_amdgcn_mfma_f32_16x16x32_bf16(A0, Bm, acc[mm][0], 0, 0, 0);
            acc[mm][1] = __builtin_amdgcn_mfma_f32_16x16x32_bf16(A1, Bm, acc[mm][1], 0, 0, 0);
        }
    }

    if (ct2 < 2) {
        short* dst = (ct2 == 0) ? q : k;
        const float scale = (ct2 == 0) ? QK_SCALE_L2E : 1.0f;
        #pragma unroll
        for (int mm = 0; mm < 4; ++mm) {
            #pragma unroll
            for (int nn = 0; nn < 2; ++nn) {
                const int d  = n0 + nn * 16 + 4 * g;
                const int h  = d >> 5, dh = d & 31;
                const int jb = ct2 * 128 + d;
                const float b0 = bqkv[e * 384 + jb + 0];
                const float b1 = bqkv[e * 384 + jb + 1];
                const float b2 = bqkv[e * 384 + jb + 2];
                const float b3 = bqkv[e * 384 + jb + 3];
                const int m  = rt * 128 + m0 + mm * 16 + l15;
                const int bb = m >> 9, s = m & 511;
                bf16x4 o;
                o[0] = f2bf((acc[mm][nn][0] + b0) * scale);
                o[1] = f2bf((acc[mm][nn][1] + b1) * scale);
                o[2] = f2bf((acc[mm][nn][2] + b2) * scale);
                o[3] = f2bf((acc[mm][nn][3] + b3) * scale);
                *(bf16x4*)&dst[((((size_t)e * B_ + bb) * H_ + h) * S_ + s) * DH_ + dh] = o;
            }
        }
    } else {
        __syncthreads();
        float (*rp)[132] = (float(*)[132])lds;
        #pragma unroll
        for (int mm = 0; mm < 4; ++mm) {
            #pragma unroll
            for (int nn = 0; nn < 2; ++nn) {
                const int jl = n0 + nn * 16 + 4 * g;
                const int ml = m0 + mm * 16 + l15;
                rp[jl + 0][ml] = acc[mm][nn][0];
                rp[jl + 1][ml] = acc[mm][nn][1];
                rp[jl + 2][ml] = acc[mm][nn][2];
                rp[jl + 3][ml] = acc[mm][nn][3];
            }
        }
        __syncthreads();
        const int bb = (rt * 128) >> 9;
        const int sb = (rt * 128) & 511;
        #pragma unroll
        for (int p = 0; p < 4; ++p) {
            int task = tid + p * 512;
            int jl = task >> 4, sc = (task & 15) * 8;
            const int h = jl >> 5, dh = jl & 31;
            const float bias = bqkv[e * 384 + 256 + jl];
            bf16x8 o;
            #pragma unroll
            for (int j = 0; j < 8; ++j) o[j] = f2bf(rp[jl][sc + j] + bias);
            *(bf16x8*)&v[((((size_t)e * B_ + bb) * H_ + h) * DH_ + dh) * S_ + sb + sc] = o;
        }
    }
}

// ---------------------------------------------------------------------------
// Kernel 2: flash attention, barrier-free (r15 base). Contiguous-k QK^T
// frags (b128 ka, 16B bq); PV keeps split va (P layout dictates). Softmax
// denominator accumulated via ones-MFMA (no VALU adds, no end shuffles).
// ---------------------------------------------------------------------------
__global__ __launch_bounds__(512) void attn_kernel(
    const short* __restrict__ q, const short* __restrict__ k,
    const short* __restrict__ vt, short* __restrict__ ctxbf)
{
    extern __shared__ __align__(16) char smem[];
    char* Kbase  = smem;            // [512 rows][80 B]
    char* VTbase = smem + 40960;    // [32 rows][1040 B]

    const int bh  = blockIdx.x;   // 0..31
    const int e   = blockIdx.y;   // 0..15
    const int tid = threadIdx.x;
    const int w    = tid >> 6;
    const int lane = tid & 63;
    const int l15  = lane & 15;
    const int g    = lane >> 4;

    const size_t base = ((size_t)e * 32 + bh) * (S_ * DH_);
    const short* qg = q  + base;
    const short* kg = k  + base;
    const short* vg = vt + base;

    // ---- stage full K: thread t copies row t (64 B) ----
    {
        const uint4* src = (const uint4*)(kg + (size_t)tid * DH_);
        uint4* dst = (uint4*)(Kbase + (size_t)tid * 80);
        dst[0] = src[0]; dst[1] = src[1]; dst[2] = src[2]; dst[3] = src[3];
    }
    // ---- stage full V^T ----
    {
        int d = tid >> 4, c0 = (tid & 15) * 32;
        const uint4* src = (const uint4*)(vg + (size_t)d * S_ + c0);
        uint4* dst = (uint4*)(VTbase + (size_t)d * 1040 + c0 * 2);
        dst[0] = src[0]; dst[1] = src[1]; dst[2] = src[2]; dst[3] = src[3];
    }
    // ---- Q fragments: contiguous-k (d = 8g..8g+7), single 16B loads ----
    bf16x8 bq[4];
    #pragma unroll
    for (int qf = 0; qf < 4; ++qf) {
        const short* qp = qg + (size_t)(w * 64 + qf * 16 + l15) * DH_;
        bq[qf] = *(const bf16x8*)(qp + 8 * g);
    }
    __syncthreads();   // the ONLY barrier

    // all-ones bf16 A-fragment for the denominator MFMA
    bf16x8 ones;
    #pragma unroll
    for (int j = 0; j < 8; ++j) ones[j] = (short)0x3F80;

    f32x4 acc0[4] = {}, acc1[4] = {};
    f32x4 accS[4] = {};   // denominator accumulator (all D-rows identical)

    for (int kt = 0; kt < 16; ++kt) {
        // K frags, contiguous-k: single b128 per 16-key tile
        const char* kp = Kbase + (size_t)(kt * 32 + l15) * 80 + g * 16;
        bf16x8 ka0 = *(const bf16x8*)kp;
        bf16x8 ka1 = *(const bf16x8*)(kp + 16 * 80);
        // V frags, old split convention (matches P/D layout)
        const int keyb = kt * 32;
        const char* vp = VTbase + (size_t)l15 * 1040 + (keyb + 4 * g) * 2;
        bf16x8 va0 = cat8(*(const bf16x4*)vp, *(const bf16x4*)(vp + 32));
        const char* vq = vp + 16 * 1040;
        bf16x8 va1 = cat8(*(const bf16x4*)vq, *(const bf16x4*)(vq + 32));

        #pragma unroll
        for (int qf = 0; qf < 4; ++qf) {
            f32x4 z = {0.f, 0.f, 0.f, 0.f};
            f32x4 s0 = __builtin_amdgcn_mfma_f32_16x16x32_bf16(ka0, bq[qf], z, 0, 0, 0);
            f32x4 s1 = __builtin_amdgcn_mfma_f32_16x16x32_bf16(ka1, bq[qf], z, 0, 0, 0);
            float p0 = __builtin_amdgcn_exp2f(s0[0]);
            float p1 = __builtin_amdgcn_exp2f(s0[1]);
            float p2 = __builtin_amdgcn_exp2f(s0[2]);
            float p3 = __builtin_amdgcn_exp2f(s0[3]);
            float p4 = __builtin_amdgcn_exp2f(s1[0]);
            float p5 = __builtin_amdgcn_exp2f(s1[1]);
            float p6 = __builtin_amdgcn_exp2f(s1[2]);
            float p7 = __builtin_amdgcn_exp2f(s1[3]);
            uint4 uu = make_uint4(pk2(p0, p1), pk2(p2, p3),
                                  pk2(p4, p5), pk2(p6, p7));
            bf16x8 pf = __builtin_bit_cast(bf16x8, uu);
            acc0[qf] = __builtin_amdgcn_mfma_f32_16x16x32_bf16(va0, pf, acc0[qf], 0, 0, 0);
            acc1[qf] = __builtin_amdgcn_mfma_f32_16x16x32_bf16(va1, pf, acc1[qf], 0, 0, 0);
            accS[qf] = __builtin_amdgcn_mfma_f32_16x16x32_bf16(ones, pf, accS[qf], 0, 0, 0);
        }
    }

    // ---- ctx write: denominator = accS[qf][0] (full 512-key sum, per-lane) --
    const int b = bh >> 2, h = bh & 3;
    #pragma unroll
    for (int qf = 0; qf < 4; ++qf) {
        const float inv = 1.0f / accS[qf][0];
        const int qrow = w * 64 + qf * 16 + l15;
        short* cg = ctxbf + (((size_t)(e * B_ + b) * S_ + qrow) * D_ + h * DH_);
        bf16x4 o0, o1;
        #pragma unroll
        for (int r = 0; r < 4; ++r) {
            o0[r] = f2bf(acc0[qf][r] * inv);
            o1[r] = f2bf(acc1[qf][r] * inv);
        }
        *(bf16x4*)&cg[4 * g]      = o0;
        *(bf16x4*)&cg[16 + 4 * g] = o1;
    }
}

// ---------------------------------------------------------------------------
// Kernel 3: head, 512-thr blocks, 128 rows. Contiguous-k frags (no cat8).
// ---------------------------------------------------------------------------
__global__ __launch_bounds__(512) void head_mfma_kernel(
    const short* __restrict__ ctxbf,  // [E][4096][128] bf16
    const short* __restrict__ wobf,   // [E][128][128] bf16
    const float* __restrict__ bo,     // [E][128]
    const short* __restrict__ w1bf,   // [E][64][128] bf16
    const float* __restrict__ b1,     // [E][64]
    const float* __restrict__ W2,     // [E][64]
    const float* __restrict__ b2,     // [E]
    float* __restrict__ out)          // [B][S][E]
{
    extern __shared__ __align__(16) char smem[];
    short (*Wos)[136] = (short(*)[136])smem;
    short (*cts)[136] = (short(*)[136])(smem + 128 * 136 * 2);

    const int mt  = blockIdx.x;   // 0..31
    const int e   = blockIdx.y;
    const int tid = threadIdx.x;
    const int w    = tid >> 6;
    const int lane = tid & 63;
    const int l15  = lane & 15;
    const int g    = lane >> 4;

    #pragma unroll
    for (int p = 0; p < 4; ++p) {
        int idx = tid + p * 512;
        int row = idx >> 4, c8 = (idx & 15) * 8;
        *(bf16x8*)&Wos[row][c8] =
            *(const bf16x8*)&wobf[((size_t)e * 128 + row) * 128 + c8];
        *(bf16x8*)&cts[row][c8] =
            *(const bf16x8*)&ctxbf[((size_t)e * M_ + mt * 128 + row) * 128 + c8];
    }
    __syncthreads();

    f32x4 accA[8] = {};
    #pragma unroll
    for (int kk = 0; kk < 128; kk += 32) {
        bf16x8 a = *(const bf16x8*)&cts[w * 16 + l15][kk + 8 * g];
        #pragma unroll
        for (int t = 0; t < 8; ++t) {
            bf16x8 bfr = *(const bf16x8*)&Wos[t * 16 + l15][kk + 8 * g];
            accA[t] = __builtin_amdgcn_mfma_f32_16x16x32_bf16(a, bfr, accA[t], 0, 0, 0);
        }
    }
    __syncthreads();

    #pragma unroll
    for (int p = 0; p < 2; ++p) {
        int idx = tid + p * 512;
        int row = idx >> 4, c8 = (idx & 15) * 8;
        *(bf16x8*)&Wos[row][c8] =
            *(const bf16x8*)&w1bf[((size_t)e * 64 + row) * 128 + c8];
    }
    #pragma unroll
    for (int t = 0; t < 8; ++t) {
        const float bov = bo[e * 128 + t * 16 + l15];
        #pragma unroll
        for (int r = 0; r < 4; ++r)
            cts[w * 16 + 4 * g + r][t * 16 + l15] = f2bf(accA[t][r] + bov);
    }
    __syncthreads();

    f32x4 accB[4] = {};
    #pragma unroll
    for (int kk = 0; kk < 128; kk += 32) {
        bf16x8 a = *(const bf16x8*)&cts[w * 16 + l15][kk + 8 * g];
        #pragma unroll
        for (int t = 0; t < 4; ++t) {
            bf16x8 bfr = *(const bf16x8*)&Wos[t * 16 + l15][kk + 8 * g];
            accB[t] = __builtin_amdgcn_mfma_f32_16x16x32_bf16(a, bfr, accB[t], 0, 0, 0);
        }
    }

    float b1v[4], w2v[4];
    #pragma unroll
    for (int t = 0; t < 4; ++t) {
        b1v[t] = b1[e * 64 + t * 16 + l15];
        w2v[t] = W2[e * 64 + t * 16 + l15];
    }
    const float b2v = b2[e];
    #pragma unroll
    for (int r = 0; r < 4; ++r) {
        float s = 0.f;
        #pragma unroll
        for (int t = 0; t < 4; ++t)
            s += fmaxf(accB[t][r] + b1v[t], 0.f) * w2v[t];
        s += __shfl_xor(s, 1);
        s += __shfl_xor(s, 2);
        s += __shfl_xor(s, 4);
        s += __shfl_xor(s, 8);
        if (l15 == 0) {
            const int m = mt * 128 + w * 16 + 4 * g + r;
            const int bb = m >> 9, ss = m & 511;
            out[((size_t)(bb * S_ + ss)) * E_ + e] = s + b2v;
        }
    }
}

// ---------------------------------------------------------------------------
extern "C" void kernel_launch(void* const* d_in, const int* in_sizes, int n_in,
                              void* d_out, int out_size, void* d_ws, size_t ws_size,
                              hipStream_t stream) {
    const float* x    = (const float*)d_in[0];
    const float* Wqkv = (const float*)d_in[1];
    const float* bqkv = (const float*)d_in[2];
    const float* Wo   = (const float*)d_in[3];
    const float* bo   = (const float*)d_in[4];
    const float* W1   = (const float*)d_in[5];
    const float* b1   = (const float*)d_in[6];
    const float* W2   = (const float*)d_in[7];
    const float* b2   = (const float*)d_in[8];
    float* out = (float*)d_out;

    const size_t SZ = (size_t)E_ * B_ * H_ * S_ * DH_;  // 8,388,608 elements
    short* qb    = (short*)d_ws;
    short* kb    = qb + SZ;
    short* vtb   = kb + SZ;
    short* ctxbf = vtb + SZ;                 // [E][4096][128] bf16
    short* xbf   = ctxbf + SZ;               // 524288
    short* wbf   = xbf + (size_t)M_ * D_;    // 786432
    short* wobf  = wbf + (size_t)E_ * 3 * D_ * D_;   // 262144
    short* w1bf  = wobf + (size_t)E_ * D_ * D_;      // 131072

    hipFuncSetAttribute((const void*)qkv_mfma_kernel,
                        hipFuncAttributeMaxDynamicSharedMemorySize,
                        QKV_LDS_BYTES);
    hipFuncSetAttribute((const void*)attn_kernel,
                        hipFuncAttributeMaxDynamicSharedMemorySize,
                        ATTN_LDS_BYTES);
    hipFuncSetAttribute((const void*)head_mfma_kernel,
                        hipFuncAttributeMaxDynamicSharedMemorySize,
                        HEAD_LDS_BYTES);

    convert_kernel<<<dim3(832), 256, 0, stream>>>(x, Wqkv, Wo, W1, xbf, wbf, wobf, w1bf);
    qkv_mfma_kernel<<<dim3(3, 32, 16), 512, QKV_LDS_BYTES, stream>>>(xbf, wbf, bqkv, qb, kb, vtb);
    attn_kernel<<<dim3(32, 16), 512, ATTN_LDS_BYTES, stream>>>(qb, kb, vtb, ctxbf);
    head_mfma_kernel<<<dim3(32, 16), 512, HEAD_LDS_BYTES, stream>>>(ctxbf, wobf, bo, w1bf, b1, W2, b2, out);
}

// Round 21
// 68.798 us; speedup vs baseline: 1.1026x; 1.0111x over previous
//
#include <hip/hip_runtime.h>
#include <hip/hip_bf16.h>

// EventSpecificTimingHeads: E=16 per-event attention heads on shared features.
// Round 21: continue r20's instruction-count attack. (1) V stored in permuted
// key order (pos g*8+hi*4+r <- key hi*16+4g+r per 32-block) so attn's PV
// A-frags are single b128 loads (no cat8); (2) pk2 packing in convert and
// qkv epilogues. Skeleton identical to r20 (ones-MFMA denom, contiguous-k).

#define E_ 16
#define B_ 8
#define S_ 512
#define D_ 128
#define H_ 4
#define DH_ 32
#define H2_ 64
#define M_ (B_ * S_)
// 1/sqrt(32) * log2(e): scores come out of QK^T in log2 domain.
#define QK_SCALE_L2E 0.25503472437616588f

#define ATTN_LDS_BYTES (512 * 80 + 32 * 1040)       // 74240
#define HEAD_LDS_BYTES (128 * 136 * 2 * 2)          // 69632
#define QKV_LDS_BYTES  (128 * 136 * 2 * 2)          // 69632

typedef __attribute__((ext_vector_type(4))) short bf16x4;
typedef __attribute__((ext_vector_type(8))) short bf16x8;
typedef __attribute__((ext_vector_type(4))) float f32x4;

__device__ __forceinline__ short f2bf(float f) {
    unsigned u = __builtin_bit_cast(unsigned, f);
    u += 0x7fffu + ((u >> 16) & 1u);   // RNE
    return (short)(u >> 16);
}

__device__ __forceinline__ unsigned pk2(float lo, float hi) {
    __hip_bfloat162 t = __float22bfloat162_rn(make_float2(lo, hi));
    unsigned r;
    __builtin_memcpy(&r, &t, sizeof(r));
    return r;
}

// ---------------------------------------------------------------------------
// Kernel 0: fp32 -> bf16 convert: x, Wqkv, Wo, W1. (convert once, read many)
// ---------------------------------------------------------------------------
__global__ __launch_bounds__(256) void convert_kernel(
    const float* __restrict__ x, const float* __restrict__ w,
    const float* __restrict__ wo, const float* __restrict__ w1,
    short* __restrict__ xbf, short* __restrict__ wbf,
    short* __restrict__ wobf, short* __restrict__ w1bf)
{
    const int XN  = (M_ * D_) / 8;             // 65536
    const int WN  = (E_ * 3 * D_ * D_) / 8;    // 98304
    const int WON = (E_ * D_ * D_) / 8;        // 32768
    const int W1N = (E_ * H2_ * D_) / 8;       // 16384
    int idx = blockIdx.x * 256 + threadIdx.x;
    const float* src; short* dst; int off;
    if (idx < XN)                        { src = x;  dst = xbf;  off = idx; }
    else if (idx < XN + WN)              { src = w;  dst = wbf;  off = idx - XN; }
    else if (idx < XN + WN + WON)        { src = wo; dst = wobf; off = idx - XN - WN; }
    else if (idx < XN + WN + WON + W1N)  { src = w1; dst = w1bf; off = idx - XN - WN - WON; }
    else return;
    float4 v0 = *(const float4*)&src[(size_t)off * 8];
    float4 v1 = *(const float4*)&src[(size_t)off * 8 + 4];
    uint4 uu = make_uint4(pk2(v0.x, v0.y), pk2(v0.z, v0.w),
                          pk2(v1.x, v1.y), pk2(v1.z, v1.w));
    *(uint4*)&dst[(size_t)off * 8] = uu;
}

// ---------------------------------------------------------------------------
// Kernel 1: QKV GEMM, 512-thr blocks, 128x128 tiles, contiguous-k frags.
// v epilogue writes PERMUTED key order (pos g*8+hi*4+r <- key hi*16+4g+r).
// ---------------------------------------------------------------------------
__global__ __launch_bounds__(512) void qkv_mfma_kernel(
    const short* __restrict__ xbf,   // [4096][128] bf16
    const short* __restrict__ wbf,   // [16][384][128] bf16
    const float* __restrict__ bqkv,  // [16][384]
    short* __restrict__ q, short* __restrict__ k, short* __restrict__ v)
{
    extern __shared__ __align__(16) char lds[];
    short (*xs)[136] = (short(*)[136])lds;
    short (*ws)[136] = (short(*)[136])(lds + 128 * 136 * 2);

    const int ct2 = blockIdx.x;  // 0..2
    const int rt  = blockIdx.y;  // 0..31
    const int e   = blockIdx.z;  // 0..15
    const int tid = threadIdx.x;
    const int w    = tid >> 6;
    const int lane = tid & 63;
    const int l15  = lane & 15;
    const int g    = lane >> 4;

    #pragma unroll
    for (int p = 0; p < 4; ++p) {
        int idx = tid + p * 512;
        int row = idx >> 4, c8 = (idx & 15) * 8;
        *(bf16x8*)&xs[row][c8] =
            *(const bf16x8*)&xbf[(size_t)(rt * 128 + row) * 128 + c8];
        *(bf16x8*)&ws[row][c8] =
            *(const bf16x8*)&wbf[((size_t)e * 384 + ct2 * 128 + row) * 128 + c8];
    }
    __syncthreads();

    const int m0 = (w >> 2) * 64;
    const int n0 = (w & 3) * 32;
    f32x4 acc[4][2] = {};

    #pragma unroll
    for (int kk = 0; kk < 128; kk += 32) {
        bf16x8 A0 = *(const bf16x8*)&ws[n0      + l15][kk + 8 * g];
        bf16x8 A1 = *(const bf16x8*)&ws[n0 + 16 + l15][kk + 8 * g];
        #pragma unroll
        for (int mm = 0; mm < 4; ++mm) {
            bf16x8 Bm = *(const bf16x8*)&xs[m0 + mm * 16 + l15][kk + 8 * g];
            acc[mm][0] = __builtin_amdgcn_mfma_f32_16x16x32_bf16(A0, Bm, acc[mm][0], 0, 0, 0);
            acc[mm][1] = __builtin_amdgcn_mfma_f32_16x16x32_bf16(A1, Bm, acc[mm][1], 0, 0, 0);
        }
    }

    if (ct2 < 2) {
        short* dst = (ct2 == 0) ? q : k;
        const float scale = (ct2 == 0) ? QK_SCALE_L2E : 1.0f;
        #pragma unroll
        for (int mm = 0; mm < 4; ++mm) {
            #pragma unroll
            for (int nn = 0; nn < 2; ++nn) {
                const int d  = n0 + nn * 16 + 4 * g;
                const int h  = d >> 5, dh = d & 31;
                const int jb = ct2 * 128 + d;
                const float b0 = bqkv[e * 384 + jb + 0];
                const float b1 = bqkv[e * 384 + jb + 1];
                const float b2 = bqkv[e * 384 + jb + 2];
                const float b3 = bqkv[e * 384 + jb + 3];
                const int m  = rt * 128 + m0 + mm * 16 + l15;
                const int bb = m >> 9, s = m & 511;
                uint2 o = make_uint2(
                    pk2((acc[mm][nn][0] + b0) * scale, (acc[mm][nn][1] + b1) * scale),
                    pk2((acc[mm][nn][2] + b2) * scale, (acc[mm][nn][3] + b3) * scale));
                *(uint2*)&dst[((((size_t)e * B_ + bb) * H_ + h) * S_ + s) * DH_ + dh] = o;
            }
        }
    } else {
        __syncthreads();
        float (*rp)[132] = (float(*)[132])lds;
        #pragma unroll
        for (int mm = 0; mm < 4; ++mm) {
            #pragma unroll
            for (int nn = 0; nn < 2; ++nn) {
                const int jl = n0 + nn * 16 + 4 * g;
                const int ml = m0 + mm * 16 + l15;
                rp[jl + 0][ml] = acc[mm][nn][0];
                rp[jl + 1][ml] = acc[mm][nn][1];
                rp[jl + 2][ml] = acc[mm][nn][2];
                rp[jl + 3][ml] = acc[mm][nn][3];
            }
        }
        __syncthreads();
        const int bb = (rt * 128) >> 9;
        const int sb = (rt * 128) & 511;
        #pragma unroll
        for (int p = 0; p < 4; ++p) {
            int task = tid + p * 512;
            int jl = task >> 4, sc = (task & 15) * 8;
            const int h = jl >> 5, dh = jl & 31;
            const float bias = bqkv[e * 384 + 256 + jl];
            // permuted key order: out pos sc+j <- key base + hi*16 + 4*gq + r
            const int kbase = sc & ~31;          // 32-key block start
            const int gq    = (sc >> 3) & 3;     // which g-slot this 8-run is
            float pv[8];
            #pragma unroll
            for (int j = 0; j < 8; ++j) {
                const int src_s = kbase + (j >> 2) * 16 + 4 * gq + (j & 3);
                pv[j] = rp[jl][src_s] + bias;
            }
            uint4 o = make_uint4(pk2(pv[0], pv[1]), pk2(pv[2], pv[3]),
                                 pk2(pv[4], pv[5]), pk2(pv[6], pv[7]));
            *(uint4*)&v[((((size_t)e * B_ + bb) * H_ + h) * DH_ + dh) * S_ + sb + sc] = o;
        }
    }
}

// ---------------------------------------------------------------------------
// Kernel 2: flash attention, barrier-free. Contiguous-k QK^T frags; PV frags
// now ALSO single b128 (V stored permuted). ones-MFMA denominator.
// ---------------------------------------------------------------------------
__global__ __launch_bounds__(512) void attn_kernel(
    const short* __restrict__ q, const short* __restrict__ k,
    const short* __restrict__ vt, short* __restrict__ ctxbf)
{
    extern __shared__ __align__(16) char smem[];
    char* Kbase  = smem;            // [512 rows][80 B]
    char* VTbase = smem + 40960;    // [32 rows][1040 B]

    const int bh  = blockIdx.x;   // 0..31
    const int e   = blockIdx.y;   // 0..15
    const int tid = threadIdx.x;
    const int w    = tid >> 6;
    const int lane = tid & 63;
    const int l15  = lane & 15;
    const int g    = lane >> 4;

    const size_t base = ((size_t)e * 32 + bh) * (S_ * DH_);
    const short* qg = q  + base;
    const short* kg = k  + base;
    const short* vg = vt + base;

    // ---- stage full K ----
    {
        const uint4* src = (const uint4*)(kg + (size_t)tid * DH_);
        uint4* dst = (uint4*)(Kbase + (size_t)tid * 80);
        dst[0] = src[0]; dst[1] = src[1]; dst[2] = src[2]; dst[3] = src[3];
    }
    // ---- stage full V^T (already permuted in memory) ----
    {
        int d = tid >> 4, c0 = (tid & 15) * 32;
        const uint4* src = (const uint4*)(vg + (size_t)d * S_ + c0);
        uint4* dst = (uint4*)(VTbase + (size_t)d * 1040 + c0 * 2);
        dst[0] = src[0]; dst[1] = src[1]; dst[2] = src[2]; dst[3] = src[3];
    }
    // ---- Q fragments: contiguous-k, single 16B loads ----
    bf16x8 bq[4];
    #pragma unroll
    for (int qf = 0; qf < 4; ++qf) {
        const short* qp = qg + (size_t)(w * 64 + qf * 16 + l15) * DH_;
        bq[qf] = *(const bf16x8*)(qp + 8 * g);
    }
    __syncthreads();   // the ONLY barrier

    bf16x8 ones;
    #pragma unroll
    for (int j = 0; j < 8; ++j) ones[j] = (short)0x3F80;

    f32x4 acc0[4] = {}, acc1[4] = {};
    f32x4 accS[4] = {};

    for (int kt = 0; kt < 16; ++kt) {
        const char* kp = Kbase + (size_t)(kt * 32 + l15) * 80 + g * 16;
        bf16x8 ka0 = *(const bf16x8*)kp;
        bf16x8 ka1 = *(const bf16x8*)(kp + 16 * 80);
        // V frags: single b128 (permuted store matches P k-slot order)
        const char* vp = VTbase + (size_t)l15 * 1040 + (size_t)kt * 64 + g * 16;
        bf16x8 va0 = *(const bf16x8*)vp;
        bf16x8 va1 = *(const bf16x8*)(vp + 16 * 1040);

        #pragma unroll
        for (int qf = 0; qf < 4; ++qf) {
            f32x4 z = {0.f, 0.f, 0.f, 0.f};
            f32x4 s0 = __builtin_amdgcn_mfma_f32_16x16x32_bf16(ka0, bq[qf], z, 0, 0, 0);
            f32x4 s1 = __builtin_amdgcn_mfma_f32_16x16x32_bf16(ka1, bq[qf], z, 0, 0, 0);
            float p0 = __builtin_amdgcn_exp2f(s0[0]);
            float p1 = __builtin_amdgcn_exp2f(s0[1]);
            float p2 = __builtin_amdgcn_exp2f(s0[2]);
            float p3 = __builtin_amdgcn_exp2f(s0[3]);
            float p4 = __builtin_amdgcn_exp2f(s1[0]);
            float p5 = __builtin_amdgcn_exp2f(s1[1]);
            float p6 = __builtin_amdgcn_exp2f(s1[2]);
            float p7 = __builtin_amdgcn_exp2f(s1[3]);
            uint4 uu = make_uint4(pk2(p0, p1), pk2(p2, p3),
                                  pk2(p4, p5), pk2(p6, p7));
            bf16x8 pf = __builtin_bit_cast(bf16x8, uu);
            acc0[qf] = __builtin_amdgcn_mfma_f32_16x16x32_bf16(va0, pf, acc0[qf], 0, 0, 0);
            acc1[qf] = __builtin_amdgcn_mfma_f32_16x16x32_bf16(va1, pf, acc1[qf], 0, 0, 0);
            accS[qf] = __builtin_amdgcn_mfma_f32_16x16x32_bf16(ones, pf, accS[qf], 0, 0, 0);
        }
    }

    // ---- ctx write: denominator from accS (full per-lane sum) ----
    const int b = bh >> 2, h = bh & 3;
    #pragma unroll
    for (int qf = 0; qf < 4; ++qf) {
        const float inv = 1.0f / accS[qf][0];
        const int qrow = w * 64 + qf * 16 + l15;
        short* cg = ctxbf + (((size_t)(e * B_ + b) * S_ + qrow) * D_ + h * DH_);
        uint2 o0 = make_uint2(pk2(acc0[qf][0] * inv, acc0[qf][1] * inv),
                              pk2(acc0[qf][2] * inv, acc0[qf][3] * inv));
        uint2 o1 = make_uint2(pk2(acc1[qf][0] * inv, acc1[qf][1] * inv),
                              pk2(acc1[qf][2] * inv, acc1[qf][3] * inv));
        *(uint2*)&cg[4 * g]      = o0;
        *(uint2*)&cg[16 + 4 * g] = o1;
    }
}

// ---------------------------------------------------------------------------
// Kernel 3: head, 512-thr blocks, 128 rows, contiguous-k frags (r20 form).
// ---------------------------------------------------------------------------
__global__ __launch_bounds__(512) void head_mfma_kernel(
    const short* __restrict__ ctxbf,  // [E][4096][128] bf16
    const short* __restrict__ wobf,   // [E][128][128] bf16
    const float* __restrict__ bo,     // [E][128]
    const short* __restrict__ w1bf,   // [E][64][128] bf16
    const float* __restrict__ b1,     // [E][64]
    const float* __restrict__ W2,     // [E][64]
    const float* __restrict__ b2,     // [E]
    float* __restrict__ out)          // [B][S][E]
{
    extern __shared__ __align__(16) char smem[];
    short (*Wos)[136] = (short(*)[136])smem;
    short (*cts)[136] = (short(*)[136])(smem + 128 * 136 * 2);

    const int mt  = blockIdx.x;   // 0..31
    const int e   = blockIdx.y;
    const int tid = threadIdx.x;
    const int w    = tid >> 6;
    const int lane = tid & 63;
    const int l15  = lane & 15;
    const int g    = lane >> 4;

    #pragma unroll
    for (int p = 0; p < 4; ++p) {
        int idx = tid + p * 512;
        int row = idx >> 4, c8 = (idx & 15) * 8;
        *(bf16x8*)&Wos[row][c8] =
            *(const bf16x8*)&wobf[((size_t)e * 128 + row) * 128 + c8];
        *(bf16x8*)&cts[row][c8] =
            *(const bf16x8*)&ctxbf[((size_t)e * M_ + mt * 128 + row) * 128 + c8];
    }
    __syncthreads();

    f32x4 accA[8] = {};
    #pragma unroll
    for (int kk = 0; kk < 128; kk += 32) {
        bf16x8 a = *(const bf16x8*)&cts[w * 16 + l15][kk + 8 * g];
        #pragma unroll
        for (int t = 0; t < 8; ++t) {
            bf16x8 bfr = *(const bf16x8*)&Wos[t * 16 + l15][kk + 8 * g];
            accA[t] = __builtin_amdgcn_mfma_f32_16x16x32_bf16(a, bfr, accA[t], 0, 0, 0);
        }
    }
    __syncthreads();

    #pragma unroll
    for (int p = 0; p < 2; ++p) {
        int idx = tid + p * 512;
        int row = idx >> 4, c8 = (idx & 15) * 8;
        *(bf16x8*)&Wos[row][c8] =
            *(const bf16x8*)&w1bf[((size_t)e * 64 + row) * 128 + c8];
    }
    #pragma unroll
    for (int t = 0; t < 8; ++t) {
        const float bov = bo[e * 128 + t * 16 + l15];
        #pragma unroll
        for (int r = 0; r < 4; ++r)
            cts[w * 16 + 4 * g + r][t * 16 + l15] = f2bf(accA[t][r] + bov);
    }
    __syncthreads();

    f32x4 accB[4] = {};
    #pragma unroll
    for (int kk = 0; kk < 128; kk += 32) {
        bf16x8 a = *(const bf16x8*)&cts[w * 16 + l15][kk + 8 * g];
        #pragma unroll
        for (int t = 0; t < 4; ++t) {
            bf16x8 bfr = *(const bf16x8*)&Wos[t * 16 + l15][kk + 8 * g];
            accB[t] = __builtin_amdgcn_mfma_f32_16x16x32_bf16(a, bfr, accB[t], 0, 0, 0);
        }
    }

    float b1v[4], w2v[4];
    #pragma unroll
    for (int t = 0; t < 4; ++t) {
        b1v[t] = b1[e * 64 + t * 16 + l15];
        w2v[t] = W2[e * 64 + t * 16 + l15];
    }
    const float b2v = b2[e];
    #pragma unroll
    for (int r = 0; r < 4; ++r) {
        float s = 0.f;
        #pragma unroll
        for (int t = 0; t < 4; ++t)
            s += fmaxf(accB[t][r] + b1v[t], 0.f) * w2v[t];
        s += __shfl_xor(s, 1);
        s += __shfl_xor(s, 2);
        s += __shfl_xor(s, 4);
        s += __shfl_xor(s, 8);
        if (l15 == 0) {
            const int m = mt * 128 + w * 16 + 4 * g + r;
            const int bb = m >> 9, ss = m & 511;
            out[((size_t)(bb * S_ + ss)) * E_ + e] = s + b2v;
        }
    }
}

// ---------------------------------------------------------------------------
extern "C" void kernel_launch(void* const* d_in, const int* in_sizes, int n_in,
                              void* d_out, int out_size, void* d_ws, size_t ws_size,
                              hipStream_t stream) {
    const float* x    = (const float*)d_in[0];
    const float* Wqkv = (const float*)d_in[1];
    const float* bqkv = (const float*)d_in[2];
    const float* Wo   = (const float*)d_in[3];
    const float* bo   = (const float*)d_in[4];
    const float* W1   = (const float*)d_in[5];
    const float* b1   = (const float*)d_in[6];
    const float* W2   = (const float*)d_in[7];
    const float* b2   = (const float*)d_in[8];
    float* out = (float*)d_out;

    const size_t SZ = (size_t)E_ * B_ * H_ * S_ * DH_;  // 8,388,608 elements
    short* qb    = (short*)d_ws;
    short* kb    = qb + SZ;
    short* vtb   = kb + SZ;
    short* ctxbf = vtb + SZ;                 // [E][4096][128] bf16
    short* xbf   = ctxbf + SZ;               // 524288
    short* wbf   = xbf + (size_t)M_ * D_;    // 786432
    short* wobf  = wbf + (size_t)E_ * 3 * D_ * D_;   // 262144
    short* w1bf  = wobf + (size_t)E_ * D_ * D_;      // 131072

    hipFuncSetAttribute((const void*)qkv_mfma_kernel,
                        hipFuncAttributeMaxDynamicSharedMemorySize,
                        QKV_LDS_BYTES);
    hipFuncSetAttribute((const void*)attn_kernel,
                        hipFuncAttributeMaxDynamicSharedMemorySize,
                        ATTN_LDS_BYTES);
    hipFuncSetAttribute((const void*)head_mfma_kernel,
                        hipFuncAttributeMaxDynamicSharedMemorySize,
                        HEAD_LDS_BYTES);

    convert_kernel<<<dim3(832), 256, 0, stream>>>(x, Wqkv, Wo, W1, xbf, wbf, wobf, w1bf);
    qkv_mfma_kernel<<<dim3(3, 32, 16), 512, QKV_LDS_BYTES, stream>>>(xbf, wbf, bqkv, qb, kb, vtb);
    attn_kernel<<<dim3(32, 16), 512, ATTN_LDS_BYTES, stream>>>(qb, kb, vtb, ctxbf);
    head_mfma_kernel<<<dim3(32, 16), 512, HEAD_LDS_BYTES, stream>>>(ctxbf, wobf, bo, w1bf, b1, W2, b2, out);
}